// Round 1
// baseline (307.663 us; speedup 1.0000x reference)
//
#include <hip/hip_runtime.h>
#include <math.h>

#define HIDDEN 1024
#define SEQ 2048
#define NF 94
#define PI 256
#define NUM_TOKEN 5

// Block-wide sum of two floats (256 threads = 4 waves of 64).
__device__ __forceinline__ void block_sum2(float& a, float& b, float* scr, int tid) {
    #pragma unroll
    for (int off = 32; off > 0; off >>= 1) {
        a += __shfl_down(a, off, 64);
        b += __shfl_down(b, off, 64);
    }
    const int lane = tid & 63, wv = tid >> 6;
    __syncthreads();                 // protect scr from previous use
    if (lane == 0) { scr[wv] = a; scr[4 + wv] = b; }
    __syncthreads();
    a = scr[0] + scr[1] + scr[2] + scr[3];
    b = scr[4] + scr[5] + scr[6] + scr[7];
}

__global__ __launch_bounds__(256)
void blackhole_emb_kernel(const int* __restrict__ ids,
                          const float* __restrict__ vals,
                          const int* __restrict__ fmts,
                          const float* __restrict__ Ww,
                          const float* __restrict__ Wp,
                          const float* __restrict__ Wt,
                          const float* __restrict__ lng,
                          const float* __restrict__ lnb,
                          const float* __restrict__ w1,
                          const float* __restrict__ b1,
                          const float* __restrict__ w2,
                          const float* __restrict__ b2,
                          const float* __restrict__ plng,
                          const float* __restrict__ plnb,
                          float* __restrict__ out)
{
    __shared__ float sh_feats[NF];
    __shared__ float sh_h[PI];
    __shared__ float sh_num[HIDDEN];
    __shared__ float scr[8];

    const int token = blockIdx.x;
    const int s     = token & (SEQ - 1);
    const int tid   = threadIdx.x;

    const int   id   = ids[token];
    const float vraw = vals[token];
    const bool active = (id == NUM_TOKEN) && !isnan(vraw);   // block-uniform

    // ---- text embedding: word + pos + type0, 4 dims/thread via float4 ----
    const float4 aw = ((const float4*)(Ww + (size_t)id * HIDDEN))[tid];
    const float4 ap = ((const float4*)(Wp + (size_t)s  * HIDDEN))[tid];
    const float4 at = ((const float4*)Wt)[tid];
    float x[4] = { aw.x + ap.x + at.x, aw.y + ap.y + at.y,
                   aw.z + ap.z + at.z, aw.w + ap.w + at.w };

    if (active) {
        const double    v    = (double)vraw;
        const double    av   = fabs(v);
        const long long bits = __double_as_longlong(v);
        const double    fl   = floor(av);
        const int       fmt  = fmts[token];

        // ---- 94 features, one per thread ----
        if (tid < NF) {
            float f;
            if (tid < 64) {
                // torch 1<<63 overflow: bit 63 feature is always 0
                f = (tid < 63 && ((bits >> tid) & 1LL)) ? 1.0f : 0.0f;
            } else if (tid < 74) {
                const int units = (int)fmin(fmax(fmod(fl, 10.0), 0.0), 9.0);
                f = (tid - 64 == units) ? 1.0f : 0.0f;
            } else if (tid < 84) {
                const int tens = (int)fmin(fmax(fmod(floor(fl / 10.0), 10.0), 0.0), 9.0);
                f = (tid - 74 == tens) ? 1.0f : 0.0f;
            } else {
                switch (tid - 84) {
                    case 0: f = (float)log(av + 1e-6); break;                       // log_v
                    case 1: f = (v > 0.0) ? 1.0f : ((v < 0.0) ? -1.0f : 0.0f); break; // sign
                    case 2: f = (av > 1e-6) ? (float)floor(log10(fmax(av, 1e-300))) : 0.0f; break;
                    case 3: f = (av == fl) ? 1.0f : 0.0f; break;                    // is_int
                    case 4: f = (v > 0.0) ? 1.0f : 0.0f; break;                     // is_pos
                    case 5: f = (v == 0.0) ? 1.0f : 0.0f; break;                    // is_zero
                    case 6: f = (v < 0.0) ? 1.0f : 0.0f; break;                     // is_neg
                    case 7: {                                                       // is_pow2
                        const bool   pos_int = (v == floor(v)) && (v > 0.0);
                        const double l2      = log2(fmax(v, 1.0));
                        f = (pos_int && (l2 == floor(l2))) ? 1.0f : 0.0f;
                        break;
                    }
                    case 8:  f = (fmt == 0) ? 1.0f : 0.0f; break;
                    default: f = (fmt == 1) ? 1.0f : 0.0f; break;
                }
            }
            sh_feats[tid] = f;
        }
        __syncthreads();

        // ---- h = gelu(feats @ w1 + b1): one of 256 outputs per thread ----
        float acc = b1[tid];
        #pragma unroll 2
        for (int k = 0; k < NF; ++k)
            acc = fmaf(sh_feats[k], w1[k * PI + tid], acc);   // broadcast LDS + coalesced w1
        acc = 0.5f * acc * (1.0f + erff(acc * 0.70710678118654752f));  // exact gelu
        sh_h[tid] = acc;
        __syncthreads();

        // ---- num = h @ w2 + b2: 4 strided outputs/thread (coalesced w2 rows) ----
        float n0 = b2[tid], n1 = b2[tid + 256], n2 = b2[tid + 512], n3 = b2[tid + 768];
        for (int k = 0; k < PI; ++k) {
            const float  hk = sh_h[k];
            const float* r  = w2 + (size_t)k * HIDDEN;
            n0 = fmaf(hk, r[tid],       n0);
            n1 = fmaf(hk, r[tid + 256], n1);
            n2 = fmaf(hk, r[tid + 512], n2);
            n3 = fmaf(hk, r[tid + 768], n3);
        }

        // ---- projection LayerNorm ----
        float sm = n0 + n1 + n2 + n3;
        float sq = n0*n0 + n1*n1 + n2*n2 + n3*n3;
        block_sum2(sm, sq, scr, tid);
        const float mu   = sm * (1.0f / HIDDEN);
        const float var  = sq * (1.0f / HIDDEN) - mu * mu;
        const float rstd = rsqrtf(var + 1e-12f);
        sh_num[tid      ] = (n0 - mu) * rstd * plng[tid      ] + plnb[tid      ];
        sh_num[tid + 256] = (n1 - mu) * rstd * plng[tid + 256] + plnb[tid + 256];
        sh_num[tid + 512] = (n2 - mu) * rstd * plng[tid + 512] + plnb[tid + 512];
        sh_num[tid + 768] = (n3 - mu) * rstd * plng[tid + 768] + plnb[tid + 768];
        __syncthreads();

        x[0] += sh_num[tid * 4 + 0];
        x[1] += sh_num[tid * 4 + 1];
        x[2] += sh_num[tid * 4 + 2];
        x[3] += sh_num[tid * 4 + 3];
    }

    // ---- final LayerNorm over 1024 dims ----
    float sm = x[0] + x[1] + x[2] + x[3];
    float sq = x[0]*x[0] + x[1]*x[1] + x[2]*x[2] + x[3]*x[3];
    block_sum2(sm, sq, scr, tid);
    const float mu   = sm * (1.0f / HIDDEN);
    const float var  = sq * (1.0f / HIDDEN) - mu * mu;
    const float rstd = rsqrtf(var + 1e-12f);

    const float4 g4 = ((const float4*)lng)[tid];
    const float4 b4 = ((const float4*)lnb)[tid];
    float4 o;
    o.x = (x[0] - mu) * rstd * g4.x + b4.x;
    o.y = (x[1] - mu) * rstd * g4.y + b4.y;
    o.z = (x[2] - mu) * rstd * g4.z + b4.z;
    o.w = (x[3] - mu) * rstd * g4.w + b4.w;
    ((float4*)(out + (size_t)token * HIDDEN))[tid] = o;
}

extern "C" void kernel_launch(void* const* d_in, const int* in_sizes, int n_in,
                              void* d_out, int out_size, void* d_ws, size_t ws_size,
                              hipStream_t stream) {
    const int*   ids  = (const int*)d_in[0];
    const float* vals = (const float*)d_in[1];
    const int*   fmts = (const int*)d_in[2];
    const float* Ww   = (const float*)d_in[3];
    const float* Wp   = (const float*)d_in[4];
    const float* Wt   = (const float*)d_in[5];
    const float* lng  = (const float*)d_in[6];
    const float* lnb  = (const float*)d_in[7];
    const float* w1   = (const float*)d_in[8];
    const float* b1   = (const float*)d_in[9];
    const float* w2   = (const float*)d_in[10];
    const float* b2   = (const float*)d_in[11];
    const float* plng = (const float*)d_in[12];
    const float* plnb = (const float*)d_in[13];
    float* out = (float*)d_out;

    const int tokens = in_sizes[0];   // 8 * 2048
    blackhole_emb_kernel<<<tokens, 256, 0, stream>>>(
        ids, vals, fmts, Ww, Wp, Wt, lng, lnb, w1, b1, w2, b2, plng, plnb, out);
}

// Round 3
// 304.499 us; speedup vs baseline: 1.0104x; 1.0104x over previous
//
#include <hip/hip_runtime.h>
#include <math.h>

#define HIDDEN 1024
#define SEQ 2048
#define NF 94
#define PI 256
#define NUM_TOKEN 5

// clang-native 16B vector (usable with __builtin_nontemporal_store)
typedef float vfloat4 __attribute__((ext_vector_type(4)));

// gelu exact (erf form), matches jax.nn.gelu(approximate=False) in fp32
__device__ __forceinline__ float gelu_exact(float a) {
    return 0.5f * a * (1.0f + erff(a * 0.70710678118654752f));
}

// Wave-per-token kernel: 64 lanes own 16 floats each (4 float4 chunks at
// stride 256). No LDS, no __syncthreads in the hot path; LN reductions are
// 64-lane shuffle butterflies. Block = 256 threads = 4 independent waves =
// 4 tokens.
__global__ __launch_bounds__(256)
void blackhole_emb_kernel(const int* __restrict__ ids,
                          const float* __restrict__ vals,
                          const int* __restrict__ fmts,
                          const float* __restrict__ Ww,
                          const float* __restrict__ Wp,
                          const float* __restrict__ Wt,
                          const float* __restrict__ lng,
                          const float* __restrict__ lnb,
                          const float* __restrict__ w1,
                          const float* __restrict__ b1,
                          const float* __restrict__ w2,
                          const float* __restrict__ b2,
                          const float* __restrict__ plng,
                          const float* __restrict__ plnb,
                          float* __restrict__ out,
                          int tokens)
{
    const int lane  = threadIdx.x & 63;
    const int wv    = threadIdx.x >> 6;
    const int token = blockIdx.x * 4 + wv;
    if (token >= tokens) return;
    const int s = token & (SEQ - 1);

    const int   id     = ids[token];            // wave-uniform -> s_load
    const float vraw   = vals[token];
    const bool  active = (id == NUM_TOKEN) && !isnan(vraw);

    const float* wrow = Ww + (size_t)id * HIDDEN;
    const float* prow = Wp + (size_t)s  * HIDDEN;
    const int    col0 = lane * 4;

    // ---- text embedding: 12 float4 loads, all independent (deep ILP) ----
    float x[4][4];
    #pragma unroll
    for (int j = 0; j < 4; ++j) {
        const int off = j * 256 + col0;
        const float4 aw = *(const float4*)(wrow + off);
        const float4 ap = *(const float4*)(prow + off);
        const float4 at = *(const float4*)(Wt   + off);
        x[j][0] = aw.x + ap.x + at.x;
        x[j][1] = aw.y + ap.y + at.y;
        x[j][2] = aw.z + ap.z + at.z;
        x[j][3] = aw.w + ap.w + at.w;
    }

    if (active) {   // wave-uniform branch; ~1 token in 50k takes this
        const double    v    = (double)vraw;
        const double    av   = fabs(v);
        const long long bits = __double_as_longlong(v);
        const double    fl   = floor(av);
        const int       fmt  = fmts[token];

        // ---- features: lane k owns feat[k] (f0) and feat[64+k] (f1) ----
        float f0 = (lane < 63 && ((bits >> lane) & 1LL)) ? 1.0f : 0.0f;
        float f1 = 0.0f;
        if (lane < 10) {
            const int units = (int)fmin(fmax(fmod(fl, 10.0), 0.0), 9.0);
            f1 = (lane == units) ? 1.0f : 0.0f;
        } else if (lane < 20) {
            const int tens = (int)fmin(fmax(fmod(floor(fl / 10.0), 10.0), 0.0), 9.0);
            f1 = (lane - 10 == tens) ? 1.0f : 0.0f;
        } else if (lane < 30) {
            switch (lane - 20) {
                case 0: f1 = (float)log(av + 1e-6); break;
                case 1: f1 = (v > 0.0) ? 1.0f : ((v < 0.0) ? -1.0f : 0.0f); break;
                case 2: f1 = (av > 1e-6) ? (float)floor(log10(fmax(av, 1e-300))) : 0.0f; break;
                case 3: f1 = (av == fl) ? 1.0f : 0.0f; break;
                case 4: f1 = (v > 0.0) ? 1.0f : 0.0f; break;
                case 5: f1 = (v == 0.0) ? 1.0f : 0.0f; break;
                case 6: f1 = (v < 0.0) ? 1.0f : 0.0f; break;
                case 7: {
                    const bool   pos_int = (v == floor(v)) && (v > 0.0);
                    const double l2      = log2(fmax(v, 1.0));
                    f1 = (pos_int && (l2 == floor(l2))) ? 1.0f : 0.0f;
                    break;
                }
                case 8: f1 = (fmt == 0) ? 1.0f : 0.0f; break;
                case 9: f1 = (fmt == 1) ? 1.0f : 0.0f; break;
            }
        }

        // ---- h[o] = gelu(feats @ w1 + b1), lane owns o = lane + 64*i ----
        float acc[4] = { b1[lane], b1[lane + 64], b1[lane + 128], b1[lane + 192] };
        for (int k = 0; k < 64; ++k) {
            const float  fk  = __shfl(f0, k, 64);
            const float* col = w1 + k * PI;
            acc[0] = fmaf(fk, col[lane],       acc[0]);
            acc[1] = fmaf(fk, col[lane + 64],  acc[1]);
            acc[2] = fmaf(fk, col[lane + 128], acc[2]);
            acc[3] = fmaf(fk, col[lane + 192], acc[3]);
        }
        for (int k = 0; k < NF - 64; ++k) {
            const float  fk  = __shfl(f1, k, 64);
            const float* col = w1 + (64 + k) * PI;
            acc[0] = fmaf(fk, col[lane],       acc[0]);
            acc[1] = fmaf(fk, col[lane + 64],  acc[1]);
            acc[2] = fmaf(fk, col[lane + 128], acc[2]);
            acc[3] = fmaf(fk, col[lane + 192], acc[3]);
        }
        float h[4];
        #pragma unroll
        for (int i = 0; i < 4; ++i) h[i] = gelu_exact(acc[i]);

        // ---- n = h @ w2 + b2, lane owns d = j*256 + lane*4 + c ----
        float n[4][4];
        #pragma unroll
        for (int j = 0; j < 4; ++j) {
            const float4 bb = *(const float4*)(b2 + j * 256 + col0);
            n[j][0] = bb.x; n[j][1] = bb.y; n[j][2] = bb.z; n[j][3] = bb.w;
        }
        #pragma unroll
        for (int i = 0; i < 4; ++i) {          // h register block (static idx)
            for (int kk = 0; kk < 64; ++kk) {
                const float  hk  = __shfl(h[i], kk, 64);
                const float* row = w2 + (size_t)(i * 64 + kk) * HIDDEN;
                #pragma unroll
                for (int j = 0; j < 4; ++j) {
                    const float4 w = *(const float4*)(row + j * 256 + col0);
                    n[j][0] = fmaf(hk, w.x, n[j][0]);
                    n[j][1] = fmaf(hk, w.y, n[j][1]);
                    n[j][2] = fmaf(hk, w.z, n[j][2]);
                    n[j][3] = fmaf(hk, w.w, n[j][3]);
                }
            }
        }

        // ---- projection LayerNorm (wave butterfly) ----
        float sm = 0.0f, sq = 0.0f;
        #pragma unroll
        for (int j = 0; j < 4; ++j)
            #pragma unroll
            for (int c = 0; c < 4; ++c) { sm += n[j][c]; sq += n[j][c] * n[j][c]; }
        #pragma unroll
        for (int off = 32; off > 0; off >>= 1) {
            sm += __shfl_xor(sm, off, 64);
            sq += __shfl_xor(sq, off, 64);
        }
        const float mu   = sm * (1.0f / HIDDEN);
        const float var  = sq * (1.0f / HIDDEN) - mu * mu;
        const float rstd = rsqrtf(var + 1e-12f);
        #pragma unroll
        for (int j = 0; j < 4; ++j) {
            const float4 g4 = *(const float4*)(plng + j * 256 + col0);
            const float4 b4 = *(const float4*)(plnb + j * 256 + col0);
            x[j][0] += (n[j][0] - mu) * rstd * g4.x + b4.x;
            x[j][1] += (n[j][1] - mu) * rstd * g4.y + b4.y;
            x[j][2] += (n[j][2] - mu) * rstd * g4.z + b4.z;
            x[j][3] += (n[j][3] - mu) * rstd * g4.w + b4.w;
        }
    }

    // ---- final LayerNorm (wave butterfly) ----
    float sm = 0.0f, sq = 0.0f;
    #pragma unroll
    for (int j = 0; j < 4; ++j)
        #pragma unroll
        for (int c = 0; c < 4; ++c) { sm += x[j][c]; sq += x[j][c] * x[j][c]; }
    #pragma unroll
    for (int off = 32; off > 0; off >>= 1) {
        sm += __shfl_xor(sm, off, 64);
        sq += __shfl_xor(sq, off, 64);
    }
    const float mu   = sm * (1.0f / HIDDEN);
    const float var  = sq * (1.0f / HIDDEN) - mu * mu;
    const float rstd = rsqrtf(var + 1e-12f);

    float* orow = out + (size_t)token * HIDDEN;
    #pragma unroll
    for (int j = 0; j < 4; ++j) {
        const int off = j * 256 + col0;
        const float4 g4 = *(const float4*)(lng + off);
        const float4 b4 = *(const float4*)(lnb + off);
        vfloat4 o;
        o.x = (x[j][0] - mu) * rstd * g4.x + b4.x;
        o.y = (x[j][1] - mu) * rstd * g4.y + b4.y;
        o.z = (x[j][2] - mu) * rstd * g4.z + b4.z;
        o.w = (x[j][3] - mu) * rstd * g4.w + b4.w;
        __builtin_nontemporal_store(o, (vfloat4*)(orow + off));
    }
}

extern "C" void kernel_launch(void* const* d_in, const int* in_sizes, int n_in,
                              void* d_out, int out_size, void* d_ws, size_t ws_size,
                              hipStream_t stream) {
    const int*   ids  = (const int*)d_in[0];
    const float* vals = (const float*)d_in[1];
    const int*   fmts = (const int*)d_in[2];
    const float* Ww   = (const float*)d_in[3];
    const float* Wp   = (const float*)d_in[4];
    const float* Wt   = (const float*)d_in[5];
    const float* lng  = (const float*)d_in[6];
    const float* lnb  = (const float*)d_in[7];
    const float* w1   = (const float*)d_in[8];
    const float* b1   = (const float*)d_in[9];
    const float* w2   = (const float*)d_in[10];
    const float* b2   = (const float*)d_in[11];
    const float* plng = (const float*)d_in[12];
    const float* plnb = (const float*)d_in[13];
    float* out = (float*)d_out;

    const int tokens = in_sizes[0];                 // 8 * 2048 = 16384
    const int blocks = (tokens + 3) / 4;            // 4 waves (tokens) per block
    blackhole_emb_kernel<<<blocks, 256, 0, stream>>>(
        ids, vals, fmts, Ww, Wp, Wt, lng, lnb, w1, b1, w2, b2, plng, plnb, out, tokens);
}